// Round 1
// baseline (633.076 us; speedup 1.0000x reference)
//
#include <hip/hip_runtime.h>
#include <stdint.h>
#include <math.h>

#define THREADS 256
#define NBINS 65536
#define CANDCAP 8128
#define NEGV (-1e30f)

static const unsigned long long EMPTY_KEY = 0xFFFFFFFFFFFFFFFFULL;

__device__ __forceinline__ uint32_t f2ord(float f) {
    uint32_t u = __float_as_uint(f);
    return (u & 0x80000000u) ? ~u : (u | 0x80000000u);
}
__device__ __forceinline__ float ord2f(uint32_t u) {
    uint32_t b = (u & 0x80000000u) ? (u ^ 0x80000000u) : ~u;
    return __uint_as_float(b);
}
__device__ __forceinline__ uint64_t mix64(uint64_t x) {
    x ^= x >> 33; x *= 0xff51afd7ed558ccdULL;
    x ^= x >> 33; x *= 0xc4ceb9fe1a85ec53ULL;
    x ^= x >> 33; return x;
}

// ---- stage insert: per box, per offset, compute HNMS key and atomicMax
//      (ord(score)<<32 | ~idx) into a per-offset hash table. ----
__global__ void k_insert(const float4* __restrict__ rects,
                         const float* __restrict__ svals,
                         const float* __restrict__ offs, int num_off,
                         uint64_t* __restrict__ keysT,
                         uint64_t* __restrict__ valsT,
                         uint32_t* __restrict__ slotidx,
                         int N, uint32_t mask, uint32_t cap) {
#pragma clang fp contract(off)
    __shared__ float powtab[64];
    __shared__ float soff[32];
    int t = threadIdx.x;
    if (t < 64) powtab[t] = (float)pow((double)1.4f, (double)(t - 24));
    if (t < num_off * 4 && t < 32) soff[t] = offs[t];
    __syncthreads();
    int i = blockIdx.x * blockDim.x + t;
    if (i >= N) return;

    float4 r = rects[i];
    float s = svals[i];
    uint64_t packed = ((uint64_t)f2ord(s) << 32) | (uint32_t)(~(uint32_t)i);

    // lg = f32(log(1.4f)) correctly rounded; log in double -> correctly-rounded f32
    const float lg = (float)log((double)1.4f);
    float Lw = (float)log((double)(r.z * 0.0625f)) / lg;
    float Lh = (float)log((double)(r.w * 0.0625f)) / lg;

    for (int k = 0; k < num_off; ++k) {
        float dw = soff[k * 4 + 0], dh = soff[k * 4 + 1];
        float dx = soff[k * 4 + 2], dy = soff[k * 4 + 3];
        float qw = floorf(Lw + dw);
        float qh = floorf(Lh + dh);
        int iw = (int)qw, ih = (int)qh;
        int tw = iw + 24; tw = tw < 0 ? 0 : (tw > 63 ? 63 : tw);
        int th = ih + 24; th = th < 0 ? 0 : (th > 63 ? 63 : th);
        float cellx = 9.6f * powtab[tw];   // alpha*w0 = 9.6f (f32), * f32 pow
        float celly = 9.6f * powtab[th];
        float qx = floorf(r.x / cellx + dx);
        float qy = floorf(r.y / celly + dy);
        int ix = (int)qx, iy = (int)qy;
        uint32_t keyA = ((uint32_t)(iw & 0xffff) << 16) | (uint32_t)(ih & 0xffff);
        uint32_t keyB = ((uint32_t)(ix & 0xffff) << 16) | (uint32_t)(iy & 0xffff);
        uint64_t key = ((uint64_t)keyA << 32) | keyB;

        uint64_t* keys = keysT + (size_t)k * cap;
        uint64_t* vals = valsT + (size_t)k * cap;
        uint32_t slot = (uint32_t)mix64(key) & mask;
        while (true) {
            uint64_t cur = keys[slot];
            if (cur == key) break;
            if (cur == EMPTY_KEY) {
                uint64_t prev = atomicCAS((unsigned long long*)&keys[slot],
                                          EMPTY_KEY, (unsigned long long)key);
                if (prev == EMPTY_KEY || prev == (unsigned long long)key) break;
            }
            slot = (slot + 1) & mask;
        }
        atomicMax((unsigned long long*)&vals[slot], (unsigned long long)packed);
        slotidx[(size_t)k * N + i] = slot;
    }
}

// ---- stage1 resolve: keep iff winner of all buckets; mscore = keep?score:NEG ----
__global__ void k_resolve1(const float* __restrict__ scores,
                           const uint64_t* __restrict__ valsT,
                           const uint32_t* __restrict__ slotidx,
                           float* __restrict__ mscore,
                           int N, int num_off, uint32_t cap) {
    int i = blockIdx.x * blockDim.x + threadIdx.x;
    if (i >= N) return;
    bool keep = true;
    for (int k = 0; k < num_off; ++k) {
        uint64_t v = valsT[(size_t)k * cap + slotidx[(size_t)k * N + i]];
        keep = keep && ((uint32_t)(~(uint32_t)v) == (uint32_t)i);
    }
    mscore[i] = keep ? scores[i] : NEGV;
}

// ---- stage2 resolve: keep2 via IoU against bucket representative; combine;
//      write final scores and histogram kept scores. ----
__global__ void k_resolve2(const float4* __restrict__ rects,
                           const float* __restrict__ scores,
                           const float* __restrict__ mscore,
                           const uint64_t* __restrict__ valsT,
                           const uint32_t* __restrict__ slotidx,
                           float* __restrict__ finals,
                           uint32_t* __restrict__ hist,
                           int N, int num_off, uint32_t cap) {
#pragma clang fp contract(off)
    int i = blockIdx.x * blockDim.x + threadIdx.x;
    if (i >= N) return;
    float4 a = rects[i];
    bool keep = (mscore[i] >= 0.0f);
    for (int k = 0; k < num_off && keep; ++k) {
        uint64_t v = valsT[(size_t)k * cap + slotidx[(size_t)k * N + i]];
        uint32_t rep = ~(uint32_t)v;
        if (rep != (uint32_t)i) {
            float4 b = rects[rep];
            float ax1 = a.x - 0.5f * a.z, ay1 = a.y - 0.5f * a.w;
            float ax2 = a.x + 0.5f * a.z, ay2 = a.y + 0.5f * a.w;
            float bx1 = b.x - 0.5f * b.z, by1 = b.y - 0.5f * b.w;
            float bx2 = b.x + 0.5f * b.z, by2 = b.y + 0.5f * b.w;
            float iw = fminf(ax2, bx2) - fmaxf(ax1, bx1); iw = fmaxf(iw, 0.0f);
            float ih = fminf(ay2, by2) - fmaxf(ay1, by1); ih = fmaxf(ih, 0.0f);
            float inter = iw * ih;
            float uni = a.z * a.w + b.z * b.w - inter;
            float iou = inter / fmaxf(uni, 1e-12f);
            keep = keep && (iou <= 0.5f);
        }
    }
    float s = scores[i];
    finals[i] = keep ? s : NEGV;
    if (keep) {
        int b = (int)(s * 65536.0f);
        b = b < 0 ? 0 : (b > NBINS - 1 ? NBINS - 1 : b);
        atomicAdd(&hist[b], 1u);
    }
}

// ---- threshold bin: largest T with count(bin >= T) >= K ----
__global__ void k_thresh(const uint32_t* __restrict__ hist, int* scalars, int K) {
    __shared__ uint32_t sh[1024];
    __shared__ int tmax;
    __shared__ uint32_t running_s;
    int t = threadIdx.x;
    if (t == 0) { running_s = 0; scalars[0] = 0; }
    __syncthreads();
    for (int base = NBINS - 1024; base >= 0; base -= 1024) {
        if (t == 0) tmax = -1;
        sh[t] = hist[base + t];
        __syncthreads();
        for (int off = 1; off < 1024; off <<= 1) {
            uint32_t v = (t + off < 1024) ? sh[t + off] : 0u;
            __syncthreads();
            sh[t] += v;
            __syncthreads();
        }
        if (running_s + sh[t] >= (uint32_t)K) atomicMax(&tmax, t);
        __syncthreads();
        if (tmax >= 0) {
            if (t == 0) scalars[0] = base + tmax;
            return;
        }
        if (t == 0) running_s += sh[0];
        __syncthreads();
    }
}

// ---- compact candidates above threshold bin ----
__global__ void k_compact(const float* __restrict__ finals,
                          uint64_t* __restrict__ cand, int* scalars, int N) {
    int i = blockIdx.x * blockDim.x + threadIdx.x;
    if (i >= N) return;
    float v = finals[i];
    if (v >= 0.0f) {
        int b = (int)(v * 65536.0f);
        b = b < 0 ? 0 : (b > NBINS - 1 ? NBINS - 1 : b);
        if (b >= scalars[0]) {
            int pos = atomicAdd(&scalars[1], 1);
            if (pos < CANDCAP)
                cand[pos] = ((uint64_t)f2ord(v) << 32) | (uint32_t)(~(uint32_t)i);
        }
    }
}

// ---- exact rank (value desc, idx asc) and emit [rects[idx], val] rows ----
__global__ void k_topk(const float4* __restrict__ rects,
                       const uint64_t* __restrict__ cand,
                       const int* __restrict__ scalars,
                       float* __restrict__ out, int K) {
    __shared__ uint64_t sc[CANDCAP];
    int t = threadIdx.x;
    int M = scalars[1]; if (M > CANDCAP) M = CANDCAP;
    for (int j = t; j < M; j += blockDim.x) sc[j] = cand[j];
    __syncthreads();
    for (int j = t; j < M; j += blockDim.x) {
        uint64_t me = sc[j];
        int rank = 0;
        for (int k = 0; k < M; ++k) rank += (sc[k] > me) ? 1 : 0;
        if (rank < K) {
            uint32_t idx = ~(uint32_t)me;
            float v = ord2f((uint32_t)(me >> 32));
            float4 r = rects[idx];
            float* o = out + (size_t)rank * 5;
            o[0] = r.x; o[1] = r.y; o[2] = r.z; o[3] = r.w; o[4] = v;
        }
    }
}

extern "C" void kernel_launch(void* const* d_in, const int* in_sizes, int n_in,
                              void* d_out, int out_size, void* d_ws, size_t ws_size,
                              hipStream_t stream) {
    const float4* rects = (const float4*)d_in[0];
    const float* scores = (const float*)d_in[1];
    const float* off1 = (const float*)d_in[2];
    const float* off2 = (const float*)d_in[3];
    int N = in_sizes[0] / 4;
    int num1 = in_sizes[2] / 4;
    int num2 = in_sizes[3] / 4;
    int NT = num1 > num2 ? num1 : num2;
    int K = out_size / 5;  // == max_proposals
    float* out = (float*)d_out;

    // pick hash-table capacity by workspace size (load factor <= ~0.5 preferred;
    // 2^20 still strictly > N so probing always terminates)
    uint32_t cap = 1u << 21;
    {
        size_t need = (size_t)NT * cap * 16 + (size_t)NBINS * 4 + 256 +
                      (size_t)CANDCAP * 8 + (size_t)NT * N * 4 + (size_t)N * 8;
        if (need > ws_size) cap = 1u << 20;
    }
    uint32_t mask = cap - 1;

    char* p = (char*)d_ws;
    uint64_t* keysT = (uint64_t*)p; p += (size_t)NT * cap * 8;
    uint64_t* valsT = (uint64_t*)p; p += (size_t)NT * cap * 8;
    uint32_t* hist  = (uint32_t*)p; p += (size_t)NBINS * 4;
    int* scalars    = (int*)p;      p += 256;
    uint64_t* cand  = (uint64_t*)p; p += (size_t)CANDCAP * 8;
    uint32_t* slotidx = (uint32_t*)p; p += (size_t)NT * N * 4;
    float* mscore   = (float*)p;    p += (size_t)N * 4;
    float* finals   = (float*)p;

    size_t tblBytes = (size_t)NT * cap * 8;
    int blocks = (N + THREADS - 1) / THREADS;

    // init: keys=EMPTY, vals=0, hist=0, scalars=0 (vals..scalars contiguous)
    hipMemsetAsync(keysT, 0xFF, tblBytes, stream);
    hipMemsetAsync(valsT, 0, tblBytes + (size_t)NBINS * 4 + 256, stream);

    // stage 1
    k_insert<<<blocks, THREADS, 0, stream>>>(rects, scores, off1, num1,
                                             keysT, valsT, slotidx, N, mask, cap);
    k_resolve1<<<blocks, THREADS, 0, stream>>>(scores, valsT, slotidx, mscore,
                                               N, num1, cap);

    // re-clear tables for stage 2
    hipMemsetAsync(keysT, 0xFF, tblBytes, stream);
    hipMemsetAsync(valsT, 0, tblBytes, stream);

    // stage 2
    k_insert<<<blocks, THREADS, 0, stream>>>(rects, mscore, off2, num2,
                                             keysT, valsT, slotidx, N, mask, cap);
    k_resolve2<<<blocks, THREADS, 0, stream>>>(rects, scores, mscore, valsT,
                                               slotidx, finals, hist, N, num2, cap);

    // top-k
    k_thresh<<<1, 1024, 0, stream>>>(hist, scalars, K);
    k_compact<<<blocks, THREADS, 0, stream>>>(finals, cand, scalars, N);
    k_topk<<<1, 1024, 0, stream>>>(rects, cand, scalars, out, K);
}